// Round 4
// baseline (355.970 us; speedup 1.0000x reference)
//
#include <hip/hip_runtime.h>

#define NN 512
#define CC 1024
#define OO 256
#define VV 68
#define PP 7
#define NC (NN*CC)
#define NV_CNT 34816.0f   // N*T*V = 512*68

typedef float floatx4 __attribute__((ext_vector_type(4)));

__device__ __forceinline__ int part_of(int v){
  return (v>=17)+(v>=22)+(v>=27)+(v>=36)+(v>=42)+(v>=48);
}

// K0: repack w1 [o][c] -> w1p[cb][o] (float4 units), coalesced read.
__global__ __launch_bounds__(256) void k0_prep(const float* __restrict__ w1,
    float* __restrict__ w1p){
  int g = blockIdx.x*256 + threadIdx.x;          // f4 idx in w1: g = o*256+cb
  int o = g >> 8, cb = g & 255;
  float4 v = ((const float4*)w1)[g];
  ((float4*)w1p)[cb*256 + o] = v;
}

// K12: fused part-sum + attention + BN partials. One block per n, 256 thr.
// Phase A: ROW-DIRECT part sums — thread t owns rows c = j*256+t (j=0..3),
//   reads its row's 17 float4 straight from global (17-deep MLP; a wave's
//   loads cover a contiguous 17.4KB span, L1/L2 absorb the per-line
//   aliasing), accumulates all 7 part s/q2 with STATIC indexing (full
//   unroll -> VGPRs, no scratch), writes s -> sSl[p][c] (conflict-free),
//   keeps q2 in regs q2r[4][7]. No LDS transpose, ONE barrier total.
//   (Replaces the stg[68*129] transpose: -35KB LDS, -16 barriers vs r2.)
// Phase B: o x c GEMM (w1p from L2, 2-addr LDS broadcasts), softmax.
// Phase C: BN partials; thread owns complete parts for its rows -> direct
//   global writes, no LDS strips, no extra barriers.
// LDS ~37KB. No launch_bounds min-waves clamp (r3 lesson: forcing it
// spilled acc[8][7] to scratch: VGPR 64, WRITE_SIZE 132MB, 93->137us).
__global__ __launch_bounds__(256) void k12_att(const float* __restrict__ x,
    const float* __restrict__ w1p, const float* __restrict__ b1,
    const float* __restrict__ w2, const float* __restrict__ b2,
    float* __restrict__ att, float* __restrict__ partial){
  int n = blockIdx.x;
  int t = threadIdx.x;

  __shared__ float4 sSf4[PP*256];                // 28672 B: S[p][c] this n
  __shared__ float hred[2048];                   // 8192 B (phase B reduce)
  __shared__ float red_s[4][PP], red_m[4][PP], pre[PP], att_s[PP];
  float* sSl = (float*)sSf4;                     // [p*1024 + c]

  float q2r[4][PP];                              // per-row-group part sq-sums

  const float4* xb = (const float4*)(x + (size_t)n*CC*VV);
  #pragma unroll
  for (int j=0;j<4;j++){
    int r = j*256 + t;
    const float4* rp = xb + (size_t)r*17;
    float4 d[17];
    #pragma unroll
    for (int k=0;k<17;k++) d[k] = rp[k];
    float s[PP], q2[PP];
    #pragma unroll
    for (int p=0;p<PP;p++){ s[p]=0.f; q2[p]=0.f; }
    #pragma unroll
    for (int k=0;k<17;k++){
      #pragma unroll
      for (int c4=0;c4<4;c4++){
        int v = 4*k + c4;
        int p = part_of(v);                      // compile-time constant
        float e = (c4==0)?d[k].x:(c4==1)?d[k].y:(c4==2)?d[k].z:d[k].w;
        s[p] += e;
        q2[p] = fmaf(e, e, q2[p]);
      }
    }
    #pragma unroll
    for (int p=0;p<PP;p++){
      sSl[p*1024 + r] = s[p];
      q2r[j][p] = q2[p];
    }
  }
  __syncthreads();

  // ---- Phase B: GEMM acc[k][p] = sum_c S[c,p] * w1[o=k*32+oh, c] ----
  int oh = t & 31, ch = t >> 5;                  // ch 0..7
  float acc[8][PP];
  #pragma unroll
  for (int k=0;k<8;k++)
    #pragma unroll
    for (int p=0;p<PP;p++) acc[k][p] = 0.f;

  const float4* wp = (const float4*)w1p;
  for (int i=0;i<32;i++){
    int gcb = ch*32 + i;
    const float4* wrow = wp + (size_t)gcb*256 + oh;
    float4 w[8];
    #pragma unroll
    for (int k=0;k<8;k++) w[k] = wrow[32*k];
    #pragma unroll
    for (int p=0;p<PP;p++){
      float4 sv = sSf4[p*256 + gcb];             // 2 addrs/wave broadcast
      #pragma unroll
      for (int k=0;k<8;k++){
        acc[k][p] = fmaf(w[k].x, sv.x, acc[k][p]);
        acc[k][p] = fmaf(w[k].y, sv.y, acc[k][p]);
        acc[k][p] = fmaf(w[k].z, sv.z, acc[k][p]);
        acc[k][p] = fmaf(w[k].w, sv.w, acc[k][p]);
      }
    }
  }

  // reduce over ch, mean/max over o, softmax over p
  const float inv_cnt[PP] = {1.f/17.f,1.f/5.f,1.f/5.f,1.f/9.f,1.f/6.f,1.f/6.f,1.f/20.f};
  float bo = b1[t];
  float h[PP];
  #pragma unroll
  for (int p=0;p<PP;p++){
    __syncthreads();
    #pragma unroll
    for (int k=0;k<8;k++) hred[ch*256 + k*32 + oh] = acc[k][p];
    __syncthreads();
    float hs = 0.f;
    #pragma unroll
    for (int c8=0;c8<8;c8++) hs += hred[c8*256 + t];
    h[p] = fmaf(hs, inv_cnt[p], bo);
  }

  int lane = t & 63, wid = t >> 6;
  #pragma unroll
  for (int p=0;p<PP;p++){
    float sm = h[p], mx = h[p];
    #pragma unroll
    for (int off=32; off>0; off>>=1){
      sm += __shfl_down(sm, off, 64);
      mx = fmaxf(mx, __shfl_down(mx, off, 64));
    }
    if (lane==0){ red_s[wid][p]=sm; red_m[wid][p]=mx; }
  }
  __syncthreads();
  if (t < PP){
    int p = t;
    float sm = red_s[0][p]+red_s[1][p]+red_s[2][p]+red_s[3][p];
    float mx = fmaxf(fmaxf(red_m[0][p],red_m[1][p]),
                     fmaxf(red_m[2][p],red_m[3][p]));
    pre[p] = w2[0]*(sm*(1.f/(float)OO)) + w2[1]*mx + b2[0];
  }
  __syncthreads();
  if (t == 0){
    float m = pre[0];
    #pragma unroll
    for (int p=1;p<PP;p++) m = fmaxf(m, pre[p]);
    float e[PP], sum=0.f;
    #pragma unroll
    for (int p=0;p<PP;p++){ e[p] = expf(pre[p]-m); sum += e[p]; }
    float inv = 1.f/sum;
    #pragma unroll
    for (int p=0;p<PP;p++){
      float a = e[p]*inv;
      att_s[p] = a;
      att[n*PP+p] = a;
    }
  }
  __syncthreads();

  // ---- Phase C: BN partials (no extra barriers, no LDS strips) ----
  float a[PP], a2[PP];
  #pragma unroll
  for (int p=0;p<PP;p++){ a[p] = att_s[p]; a2[p] = a[p]*a[p]; }
  #pragma unroll
  for (int j=0;j<4;j++){
    int c = j*256 + t;
    float sm = 0.f, sq = 0.f;
    #pragma unroll
    for (int p=0;p<PP;p++){
      sm = fmaf(a[p],  sSl[p*1024 + c], sm);
      sq = fmaf(a2[p], q2r[j][p],       sq);
    }
    partial[n*2048 + c]        = sm;
    partial[n*2048 + 1024 + c] = sq;
  }
}

// K3b: single-dispatch reduce over n + BN finalize. 32 blocks x 256 thr.
__global__ __launch_bounds__(256) void k3b_finalize(const float* __restrict__ partial,
    const float* __restrict__ gamma, const float* __restrict__ beta,
    float* __restrict__ scsh){
  __shared__ float rs[8][32], rq[8][32];
  int cl = threadIdx.x & 31, grp = threadIdx.x >> 5;
  int c = blockIdx.x*32 + cl;
  float sm=0.f, sq=0.f;
  for (int i=0;i<64;i++){
    int n = grp*64 + i;
    sm += partial[n*2048 + c];
    sq += partial[n*2048 + 1024 + c];
  }
  rs[grp][cl] = sm; rq[grp][cl] = sq;
  __syncthreads();
  if (threadIdx.x < 32){
    float tsm=0.f, tsq=0.f;
    #pragma unroll
    for (int g=0; g<8; g++){ tsm += rs[g][threadIdx.x]; tsq += rq[g][threadIdx.x]; }
    int cc = blockIdx.x*32 + threadIdx.x;
    float mean = tsm * (1.0f/NV_CNT);
    float var  = tsq * (1.0f/NV_CNT) - mean*mean;
    float rstd = rsqrtf(var + 1e-5f);
    float sc = gamma[cc]*rstd;
    scsh[cc]        = sc;
    scsh[1024 + cc] = beta[cc] - mean*sc;
  }
}

// K4: out = relu( x*(att_j*sc + 1) + sh ); nontemporal stores via ext_vector.
__global__ __launch_bounds__(256) void k4_out(const float* __restrict__ x,
    const float* __restrict__ att, const float* __restrict__ scsh,
    float* __restrict__ out){
  int f = blockIdx.x*256 + threadIdx.x;          // float4 index, < NC*17
  int n = blockIdx.x / 68;                       // uniform within block
  __shared__ float s_att[PP];
  if (threadIdx.x < PP) s_att[threadIdx.x] = att[n*PP + threadIdx.x];
  __syncthreads();
  int r = f/17;
  int q = f - r*17;
  int v0 = q*4;
  int c = r & (CC-1);
  float4 xv = ((const float4*)x)[f];
  float sc = scsh[c];
  float sh = scsh[1024 + c];
  float vals[4];
  #pragma unroll
  for (int j=0;j<4;j++){
    int p = part_of(v0 + j);
    float a = s_att[p];
    float e = (j==0)?xv.x:(j==1)?xv.y:(j==2)?xv.z:xv.w;
    vals[j] = fmaxf(fmaf(e, fmaf(a, sc, 1.0f), sh), 0.0f);
  }
  floatx4 ov; ov.x=vals[0]; ov.y=vals[1]; ov.z=vals[2]; ov.w=vals[3];
  __builtin_nontemporal_store(ov, ((floatx4*)out) + f);
}

extern "C" void kernel_launch(void* const* d_in, const int* in_sizes, int n_in,
                              void* d_out, int out_size, void* d_ws, size_t ws_size,
                              hipStream_t stream) {
  const float* x     = (const float*)d_in[0];
  const float* w1    = (const float*)d_in[1];
  const float* b1    = (const float*)d_in[2];
  const float* w2    = (const float*)d_in[3];
  const float* b2    = (const float*)d_in[4];
  const float* gamma = (const float*)d_in[5];
  const float* beta  = (const float*)d_in[6];
  float* out = (float*)d_out;

  float* w1p     = (float*)d_ws;                 // 256*1024 (1 MB)
  float* partial = w1p + OO*CC;                  // 512*2048 (4 MB)
  float* scsh    = partial + NN*2048;            // 2048
  float* att     = scsh + 2048;                  // 512*7
  // ~5 MB of ws; every buffer fully overwritten each call

  k0_prep     <<<256,         256, 0, stream>>>(w1, w1p);
  k12_att     <<<NN,          256, 0, stream>>>(x, w1p, b1, w2, b2, att, partial);
  k3b_finalize<<<32,          256, 0, stream>>>(partial, gamma, beta, scsh);
  k4_out      <<<(NC*17)/256, 256, 0, stream>>>(x, att, scsh, out);
}

// Round 5
// 341.918 us; speedup vs baseline: 1.0411x; 1.0411x over previous
//
#include <hip/hip_runtime.h>

#define NN 512
#define CC 1024
#define OO 256
#define VV 68
#define PP 7
#define NC (NN*CC)
#define NV_CNT 34816.0f   // N*T*V = 512*68

typedef float floatx4 __attribute__((ext_vector_type(4)));

__device__ __forceinline__ int part_of(int v){
  return (v>=17)+(v>=22)+(v>=27)+(v>=36)+(v>=42)+(v>=48);
}

// K0: repack w1 [o][c] -> w1p[cb][o] (float4 units), coalesced read.
__global__ __launch_bounds__(256) void k0_prep(const float* __restrict__ w1,
    float* __restrict__ w1p){
  int g = blockIdx.x*256 + threadIdx.x;          // f4 idx in w1: g = o*256+cb
  int o = g >> 8, cb = g & 255;
  float4 v = ((const float4*)w1)[g];
  ((float4*)w1p)[cb*256 + o] = v;
}

// K12: fused part-sum + attention + BN partials. One block per n, 512 thr.
// Design rule from R2/R4: phase-A throughput ~ (resident waves) x (MLP).
//   R2: 8 waves/CU x 9 loads -> 93us. R4: ~4 waves/CU x 17 -> 133us.
//   Here: 16 waves/CU x 9 loads.
// Phase A: row-direct, thread t owns rows r = j*512+t (j=0..1); d[9]
//   bounded staging (36 VGPR, dead before phase B); all 7 part s/q2
//   statically indexed; s -> sSl[p][c], q2 stays in q2r[2][7] (14 regs).
//   One barrier. No LDS transpose (LDS 37KB -> 2 blocks of 8 waves/CU,
//   VGPR-capped at 4 waves/SIMD if <=128).
// Phase B: o x c GEMM, 16 ch-groups; one __shfl_xor(32) folds ch-pairs so
//   hred stays 8KB; then 8-way LDS reduce, softmax over parts.
// Phase C: BN partials; thread owns complete parts for its rows -> direct
//   global writes.
// NO min-waves clamp (R3: forcing it spilled acc -> scratch, 132MB writes).
__global__ __launch_bounds__(512) void k12_att(const float* __restrict__ x,
    const float* __restrict__ w1p, const float* __restrict__ b1,
    const float* __restrict__ w2, const float* __restrict__ b2,
    float* __restrict__ att, float* __restrict__ partial){
  int n = blockIdx.x;
  int t = threadIdx.x;

  __shared__ float4 sSf4[PP*256];                // 28672 B: S[p][c] this n
  __shared__ float hred[2048];                   // 8192 B (phase B reduce)
  __shared__ float red_s[4][PP], red_m[4][PP], pre[PP], att_s[PP];
  float* sSl = (float*)sSf4;                     // [p*1024 + c]

  float q2r[2][PP];                              // per-row part sq-sums (regs)

  const float4* xb = (const float4*)(x + (size_t)n*CC*VV);
  #pragma unroll
  for (int j=0;j<2;j++){
    int r = j*512 + t;
    const float4* rp = xb + (size_t)r*17;
    float s[PP], q2[PP];
    #pragma unroll
    for (int p=0;p<PP;p++){ s[p]=0.f; q2[p]=0.f; }
    float4 d[9];
    #pragma unroll
    for (int k=0;k<9;k++) d[k] = rp[k];          // 9 outstanding loads
    #pragma unroll
    for (int k=0;k<9;k++){
      #pragma unroll
      for (int c4=0;c4<4;c4++){
        int v = 4*k + c4;                        // 0..35
        int p = part_of(v);                      // compile-time constant
        float e = (c4==0)?d[k].x:(c4==1)?d[k].y:(c4==2)?d[k].z:d[k].w;
        s[p] += e;
        q2[p] = fmaf(e, e, q2[p]);
      }
    }
    #pragma unroll
    for (int k=0;k<8;k++) d[k] = rp[9+k];        // 8 outstanding loads
    #pragma unroll
    for (int k=0;k<8;k++){
      #pragma unroll
      for (int c4=0;c4<4;c4++){
        int v = 36 + 4*k + c4;                   // 36..67
        int p = part_of(v);
        float e = (c4==0)?d[k].x:(c4==1)?d[k].y:(c4==2)?d[k].z:d[k].w;
        s[p] += e;
        q2[p] = fmaf(e, e, q2[p]);
      }
    }
    #pragma unroll
    for (int p=0;p<PP;p++){
      sSl[p*1024 + r] = s[p];
      q2r[j][p] = q2[p];
    }
  }
  __syncthreads();

  // ---- Phase B: GEMM acc[k][p] = sum_c S[c,p] * w1[o=k*32+oh, c] ----
  int oh = t & 31, ch = t >> 5;                  // ch 0..15
  float acc[8][PP];
  #pragma unroll
  for (int k=0;k<8;k++)
    #pragma unroll
    for (int p=0;p<PP;p++) acc[k][p] = 0.f;

  const float4* wp = (const float4*)w1p;
  for (int i=0;i<16;i++){
    int gcb = ch*16 + i;
    const float4* wrow = wp + (size_t)gcb*256 + oh;
    float4 w[8];
    #pragma unroll
    for (int k=0;k<8;k++) w[k] = wrow[32*k];
    #pragma unroll
    for (int p=0;p<PP;p++){
      float4 sv = sSf4[p*256 + gcb];             // 2 addrs/wave broadcast
      #pragma unroll
      for (int k=0;k<8;k++){
        acc[k][p] = fmaf(w[k].x, sv.x, acc[k][p]);
        acc[k][p] = fmaf(w[k].y, sv.y, acc[k][p]);
        acc[k][p] = fmaf(w[k].z, sv.z, acc[k][p]);
        acc[k][p] = fmaf(w[k].w, sv.w, acc[k][p]);
      }
    }
  }

  // reduce: shfl_xor(32) folds ch-pairs (16->8 groups), LDS folds 8->1,
  // then mean/max over o, softmax over p
  const float inv_cnt[PP] = {1.f/17.f,1.f/5.f,1.f/5.f,1.f/9.f,1.f/6.f,1.f/6.f,1.f/20.f};
  float bo = (t < OO) ? b1[t] : 0.f;
  int lane = t & 63, wid = t >> 6;               // wid 0..7
  float h[PP];
  #pragma unroll
  for (int p=0;p<PP;p++){
    float v8[8];
    #pragma unroll
    for (int k=0;k<8;k++) v8[k] = acc[k][p] + __shfl_xor(acc[k][p], 32, 64);
    __syncthreads();
    if (lane < 32){
      #pragma unroll
      for (int k=0;k<8;k++) hred[wid*256 + k*32 + oh] = v8[k];
    }
    __syncthreads();
    if (t < OO){
      float hs = 0.f;
      #pragma unroll
      for (int g=0;g<8;g++) hs += hred[g*256 + t];
      h[p] = fmaf(hs, inv_cnt[p], bo);
    }
  }

  if (t < OO){                                   // waves 0..3
    #pragma unroll
    for (int p=0;p<PP;p++){
      float sm = h[p], mx = h[p];
      #pragma unroll
      for (int off=32; off>0; off>>=1){
        sm += __shfl_down(sm, off, 64);
        mx = fmaxf(mx, __shfl_down(mx, off, 64));
      }
      if (lane==0){ red_s[wid][p]=sm; red_m[wid][p]=mx; }
    }
  }
  __syncthreads();
  if (t < PP){
    int p = t;
    float sm = red_s[0][p]+red_s[1][p]+red_s[2][p]+red_s[3][p];
    float mx = fmaxf(fmaxf(red_m[0][p],red_m[1][p]),
                     fmaxf(red_m[2][p],red_m[3][p]));
    pre[p] = w2[0]*(sm*(1.f/(float)OO)) + w2[1]*mx + b2[0];
  }
  __syncthreads();
  if (t == 0){
    float m = pre[0];
    #pragma unroll
    for (int p=1;p<PP;p++) m = fmaxf(m, pre[p]);
    float e[PP], sum=0.f;
    #pragma unroll
    for (int p=0;p<PP;p++){ e[p] = expf(pre[p]-m); sum += e[p]; }
    float inv = 1.f/sum;
    #pragma unroll
    for (int p=0;p<PP;p++){
      float a = e[p]*inv;
      att_s[p] = a;
      att[n*PP+p] = a;
    }
  }
  __syncthreads();

  // ---- Phase C: BN partials (direct writes, no extra barriers) ----
  float a[PP], a2[PP];
  #pragma unroll
  for (int p=0;p<PP;p++){ a[p] = att_s[p]; a2[p] = a[p]*a[p]; }
  #pragma unroll
  for (int j=0;j<2;j++){
    int c = j*512 + t;
    float sm = 0.f, sq = 0.f;
    #pragma unroll
    for (int p=0;p<PP;p++){
      sm = fmaf(a[p],  sSl[p*1024 + c], sm);
      sq = fmaf(a2[p], q2r[j][p],       sq);
    }
    partial[n*2048 + c]        = sm;
    partial[n*2048 + 1024 + c] = sq;
  }
}

// K3b: single-dispatch reduce over n + BN finalize. 32 blocks x 256 thr.
__global__ __launch_bounds__(256) void k3b_finalize(const float* __restrict__ partial,
    const float* __restrict__ gamma, const float* __restrict__ beta,
    float* __restrict__ scsh){
  __shared__ float rs[8][32], rq[8][32];
  int cl = threadIdx.x & 31, grp = threadIdx.x >> 5;
  int c = blockIdx.x*32 + cl;
  float sm=0.f, sq=0.f;
  for (int i=0;i<64;i++){
    int n = grp*64 + i;
    sm += partial[n*2048 + c];
    sq += partial[n*2048 + 1024 + c];
  }
  rs[grp][cl] = sm; rq[grp][cl] = sq;
  __syncthreads();
  if (threadIdx.x < 32){
    float tsm=0.f, tsq=0.f;
    #pragma unroll
    for (int g=0; g<8; g++){ tsm += rs[g][threadIdx.x]; tsq += rq[g][threadIdx.x]; }
    int cc = blockIdx.x*32 + threadIdx.x;
    float mean = tsm * (1.0f/NV_CNT);
    float var  = tsq * (1.0f/NV_CNT) - mean*mean;
    float rstd = rsqrtf(var + 1e-5f);
    float sc = gamma[cc]*rstd;
    scsh[cc]        = sc;
    scsh[1024 + cc] = beta[cc] - mean*sc;
  }
}

// K4: out = relu( x*(att_j*sc + 1) + sh ); nontemporal stores via ext_vector.
__global__ __launch_bounds__(256) void k4_out(const float* __restrict__ x,
    const float* __restrict__ att, const float* __restrict__ scsh,
    float* __restrict__ out){
  int f = blockIdx.x*256 + threadIdx.x;          // float4 index, < NC*17
  int n = blockIdx.x / 68;                       // uniform within block
  __shared__ float s_att[PP];
  if (threadIdx.x < PP) s_att[threadIdx.x] = att[n*PP + threadIdx.x];
  __syncthreads();
  int r = f/17;
  int q = f - r*17;
  int v0 = q*4;
  int c = r & (CC-1);
  float4 xv = ((const float4*)x)[f];
  float sc = scsh[c];
  float sh = scsh[1024 + c];
  float vals[4];
  #pragma unroll
  for (int j=0;j<4;j++){
    int p = part_of(v0 + j);
    float a = s_att[p];
    float e = (j==0)?xv.x:(j==1)?xv.y:(j==2)?xv.z:xv.w;
    vals[j] = fmaxf(fmaf(e, fmaf(a, sc, 1.0f), sh), 0.0f);
  }
  floatx4 ov; ov.x=vals[0]; ov.y=vals[1]; ov.z=vals[2]; ov.w=vals[3];
  __builtin_nontemporal_store(ov, ((floatx4*)out) + f);
}

extern "C" void kernel_launch(void* const* d_in, const int* in_sizes, int n_in,
                              void* d_out, int out_size, void* d_ws, size_t ws_size,
                              hipStream_t stream) {
  const float* x     = (const float*)d_in[0];
  const float* w1    = (const float*)d_in[1];
  const float* b1    = (const float*)d_in[2];
  const float* w2    = (const float*)d_in[3];
  const float* b2    = (const float*)d_in[4];
  const float* gamma = (const float*)d_in[5];
  const float* beta  = (const float*)d_in[6];
  float* out = (float*)d_out;

  float* w1p     = (float*)d_ws;                 // 256*1024 (1 MB)
  float* partial = w1p + OO*CC;                  // 512*2048 (4 MB)
  float* scsh    = partial + NN*2048;            // 2048
  float* att     = scsh + 2048;                  // 512*7
  // ~5 MB of ws; every buffer fully overwritten each call

  k0_prep     <<<256,         256, 0, stream>>>(w1, w1p);
  k12_att     <<<NN,          512, 0, stream>>>(x, w1p, b1, w2, b2, att, partial);
  k3b_finalize<<<32,          256, 0, stream>>>(partial, gamma, beta, scsh);
  k4_out      <<<(NC*17)/256, 256, 0, stream>>>(x, att, scsh, out);
}

// Round 6
// 326.115 us; speedup vs baseline: 1.0916x; 1.0485x over previous
//
#include <hip/hip_runtime.h>

#define NN 512
#define CC 1024
#define OO 256
#define VV 68
#define PP 7
#define NC (NN*CC)
#define NV_CNT 34816.0f   // N*T*V = 512*68

typedef float floatx4 __attribute__((ext_vector_type(4)));

__device__ __forceinline__ int part_of(int v){
  return (v>=17)+(v>=22)+(v>=27)+(v>=36)+(v>=42)+(v>=48);
}

// K0: repack w1 [o][c] -> w1p[cb][o] (float4 units), coalesced read.
__global__ __launch_bounds__(256) void k0_prep(const float* __restrict__ w1,
    float* __restrict__ w1p){
  int g = blockIdx.x*256 + threadIdx.x;          // f4 idx in w1: g = o*256+cb
  int o = g >> 8, cb = g & 255;
  float4 v = ((const float4*)w1)[g];
  ((float4*)w1p)[cb*256 + o] = v;
}

// K12: fused part-sum + attention + BN partials. One block per n, 512 thr.
// Evidence ledger: R2 (coalesced transpose, 256thr, 8 waves/CU) = 93us;
// R4/R5 (row-direct, uncoalesced 272B-stride lanes) = 133/121us -> loads
// MUST be coalesced (request-rate, not bytes). R5 also spilled at VGPR=128
// (WRITE 29.7MB). R3 = this structure but min-waves-clamped -> spill.
// This round: R3 unclamped + k-split GEMM to fit VGPR<=128 w/o spill ->
// 2 blocks x 8 waves = 16 waves/CU, coalesced phase A.
// Phase A (x8 chunks of 128 c-rows): coalesced f4 load -> LDS transpose
//   stg[v][row] (stride 129) -> part-aligned quad split (p0 | p1,p2 |
//   p3,p4 | p5,p6); S -> GEMM LDS array, sq-sums in regs q2r[8][2].
// Phase B: o x c GEMM in TWO k-passes (w[4] staging, -16 peak VGPR;
//   disjoint w1p halves so L2 traffic unchanged), 16 ch-groups, then
//   hred reduce, softmax over parts.
// Phase C: BN partials; quads 1-3 write weighted sq strips, quad 0 combines.
__global__ __launch_bounds__(512) void k12_att(const float* __restrict__ x,
    const float* __restrict__ w1p, const float* __restrict__ b1,
    const float* __restrict__ w2, const float* __restrict__ b2,
    float* __restrict__ att, float* __restrict__ partial){
  int n = blockIdx.x;
  int t = threadIdx.x;

  __shared__ float stg[68*129];                  // 35088 B; reused as hred/sqt
  __shared__ float4 sSf4[PP*256];                // 28672 B: S[p][c] this n
  __shared__ float red_s[4][PP], red_m[4][PP], pre[PP], att_s[PP];
  float* sSl  = (float*)sSf4;                    // [p*1024 + c]
  float* hred = stg;                             // 4096 floats (phase B)
  float* sqt  = stg + 4096;                      // 3*1024 floats (phase C)

  int row  = t & 127;
  int quad = t >> 7;                             // 0..3, wave-pair-uniform

  float q2r[8][2];                               // per-chunk part sq-sums (regs)
  #pragma unroll
  for (int j=0;j<8;j++){ q2r[j][0]=0.f; q2r[j][1]=0.f; }

  const float4* xb = (const float4*)(x + (size_t)n*CC*VV);
  #pragma unroll
  for (int j=0;j<8;j++){
    const float4* src = xb + j*2176;
    #pragma unroll
    for (int k=0;k<5;k++){
      int g = k*512 + t;                         // f4 idx in [0,2176)
      if (k==4 && t>=128) break;
      float4 v4 = src[g];
      int rr = g/17, q = g - rr*17;
      stg[(q*4+0)*129 + rr] = v4.x;
      stg[(q*4+1)*129 + rr] = v4.y;
      stg[(q*4+2)*129 + rr] = v4.z;
      stg[(q*4+3)*129 + rr] = v4.w;
    }
    __syncthreads();
    if (quad==0){                                // p0: v 0..16
      float s0 = 0.f;
      #pragma unroll
      for (int v=0; v<17; v++){
        float e = stg[v*129 + row];
        s0 += e; q2r[j][0] = fmaf(e, e, q2r[j][0]);
      }
      sSl[0*1024 + j*128 + row] = s0;
    } else if (quad==1){                         // p1: 17..21, p2: 22..26
      float s1=0.f, s2=0.f;
      #pragma unroll
      for (int v=17; v<22; v++){
        float e = stg[v*129 + row];
        s1 += e; q2r[j][0] = fmaf(e, e, q2r[j][0]);
      }
      #pragma unroll
      for (int v=22; v<27; v++){
        float e = stg[v*129 + row];
        s2 += e; q2r[j][1] = fmaf(e, e, q2r[j][1]);
      }
      sSl[1*1024 + j*128 + row] = s1;
      sSl[2*1024 + j*128 + row] = s2;
    } else if (quad==2){                         // p3: 27..35, p4: 36..41
      float s3=0.f, s4=0.f;
      #pragma unroll
      for (int v=27; v<36; v++){
        float e = stg[v*129 + row];
        s3 += e; q2r[j][0] = fmaf(e, e, q2r[j][0]);
      }
      #pragma unroll
      for (int v=36; v<42; v++){
        float e = stg[v*129 + row];
        s4 += e; q2r[j][1] = fmaf(e, e, q2r[j][1]);
      }
      sSl[3*1024 + j*128 + row] = s3;
      sSl[4*1024 + j*128 + row] = s4;
    } else {                                     // p5: 42..47, p6: 48..67
      float s5=0.f, s6=0.f;
      #pragma unroll
      for (int v=42; v<48; v++){
        float e = stg[v*129 + row];
        s5 += e; q2r[j][0] = fmaf(e, e, q2r[j][0]);
      }
      #pragma unroll
      for (int v=48; v<68; v++){
        float e = stg[v*129 + row];
        s6 += e; q2r[j][1] = fmaf(e, e, q2r[j][1]);
      }
      sSl[5*1024 + j*128 + row] = s5;
      sSl[6*1024 + j*128 + row] = s6;
    }
    __syncthreads();                             // stg reads done before next stage
  }

  // ---- Phase B: GEMM acc[k][p] = sum_c S[c,p] * w1[o=k*32+oh, c] ----
  // Two k-passes (k 0..3, then 4..7) to halve w-staging VGPRs.
  int oh = t & 31, ch = t >> 5;                  // ch 0..15
  float acc[8][PP];
  #pragma unroll
  for (int k=0;k<8;k++)
    #pragma unroll
    for (int p=0;p<PP;p++) acc[k][p] = 0.f;

  const float4* wp = (const float4*)w1p;
  #pragma unroll
  for (int pass=0; pass<2; ++pass){
    for (int i=0;i<16;i++){
      int gcb = ch*16 + i;
      const float4* wrow = wp + (size_t)gcb*256 + oh + 128*pass;
      float4 w[4];
      #pragma unroll
      for (int k=0;k<4;k++) w[k] = wrow[32*k];
      #pragma unroll
      for (int p=0;p<PP;p++){
        float4 sv = sSf4[p*256 + gcb];           // 2 addrs/wave broadcast
        #pragma unroll
        for (int k=0;k<4;k++){
          int kk = pass*4 + k;
          acc[kk][p] = fmaf(w[k].x, sv.x, acc[kk][p]);
          acc[kk][p] = fmaf(w[k].y, sv.y, acc[kk][p]);
          acc[kk][p] = fmaf(w[k].z, sv.z, acc[kk][p]);
          acc[kk][p] = fmaf(w[k].w, sv.w, acc[kk][p]);
        }
      }
    }
  }

  // reduce over ch (16 groups via hred), mean/max over o, softmax over p
  const float inv_cnt[PP] = {1.f/17.f,1.f/5.f,1.f/5.f,1.f/9.f,1.f/6.f,1.f/6.f,1.f/20.f};
  float bo = (t < OO) ? b1[t] : 0.f;
  float h[PP];
  #pragma unroll
  for (int p=0;p<PP;p++){
    __syncthreads();
    #pragma unroll
    for (int k=0;k<8;k++) hred[ch*256 + k*32 + oh] = acc[k][p];
    __syncthreads();
    if (t < OO){
      float hs = 0.f;
      #pragma unroll
      for (int c16=0;c16<16;c16++) hs += hred[c16*256 + t];
      h[p] = fmaf(hs, inv_cnt[p], bo);
    }
  }

  int lane = t & 63, wid = t >> 6;
  if (t < OO){                                   // waves 0..3
    #pragma unroll
    for (int p=0;p<PP;p++){
      float sm = h[p], mx = h[p];
      #pragma unroll
      for (int off=32; off>0; off>>=1){
        sm += __shfl_down(sm, off, 64);
        mx = fmaxf(mx, __shfl_down(mx, off, 64));
      }
      if (lane==0){ red_s[wid][p]=sm; red_m[wid][p]=mx; }
    }
  }
  __syncthreads();
  if (t < PP){
    int p = t;
    float sm = red_s[0][p]+red_s[1][p]+red_s[2][p]+red_s[3][p];
    float mx = fmaxf(fmaxf(red_m[0][p],red_m[1][p]),
                     fmaxf(red_m[2][p],red_m[3][p]));
    pre[p] = w2[0]*(sm*(1.f/(float)OO)) + w2[1]*mx + b2[0];
  }
  __syncthreads();
  if (t == 0){
    float m = pre[0];
    #pragma unroll
    for (int p=1;p<PP;p++) m = fmaxf(m, pre[p]);
    float e[PP], sum=0.f;
    #pragma unroll
    for (int p=0;p<PP;p++){ e[p] = expf(pre[p]-m); sum += e[p]; }
    float inv = 1.f/sum;
    #pragma unroll
    for (int p=0;p<PP;p++){
      float a = e[p]*inv;
      att_s[p] = a;
      att[n*PP+p] = a;
    }
  }
  __syncthreads();

  // ---- Phase C: BN partials ----
  float a[PP];
  #pragma unroll
  for (int p=0;p<PP;p++) a[p] = att_s[p];

  // sm partials: all 512 threads, from LDS S
  #pragma unroll
  for (int jj=0;jj<2;jj++){
    int c = jj*512 + t;
    float sm = 0.f;
    #pragma unroll
    for (int p=0;p<PP;p++) sm = fmaf(a[p], sSl[p*1024 + c], sm);
    partial[n*2048 + c] = sm;
  }

  // sq partials: quads 1..3 write weighted strips, quad 0 combines
  if (quad>0){
    int pA = (quad==1)?1:(quad==2)?3:5;
    int pB = pA + 1;
    float aA = a[pA]*a[pA], aB = a[pB]*a[pB];
    #pragma unroll
    for (int j=0;j<8;j++){
      sqt[(quad-1)*1024 + j*128 + row] = aA*q2r[j][0] + aB*q2r[j][1];
    }
  }
  __syncthreads();
  if (quad==0){
    float a0 = a[0]*a[0];
    #pragma unroll
    for (int j=0;j<8;j++){
      int c = j*128 + row;
      float sq = a0*q2r[j][0]
               + sqt[0*1024 + c] + sqt[1*1024 + c] + sqt[2*1024 + c];
      partial[n*2048 + 1024 + c] = sq;
    }
  }
}

// K3b: single-dispatch reduce over n + BN finalize. 32 blocks x 256 thr.
__global__ __launch_bounds__(256) void k3b_finalize(const float* __restrict__ partial,
    const float* __restrict__ gamma, const float* __restrict__ beta,
    float* __restrict__ scsh){
  __shared__ float rs[8][32], rq[8][32];
  int cl = threadIdx.x & 31, grp = threadIdx.x >> 5;
  int c = blockIdx.x*32 + cl;
  float sm=0.f, sq=0.f;
  for (int i=0;i<64;i++){
    int n = grp*64 + i;
    sm += partial[n*2048 + c];
    sq += partial[n*2048 + 1024 + c];
  }
  rs[grp][cl] = sm; rq[grp][cl] = sq;
  __syncthreads();
  if (threadIdx.x < 32){
    float tsm=0.f, tsq=0.f;
    #pragma unroll
    for (int g=0; g<8; g++){ tsm += rs[g][threadIdx.x]; tsq += rq[g][threadIdx.x]; }
    int cc = blockIdx.x*32 + threadIdx.x;
    float mean = tsm * (1.0f/NV_CNT);
    float var  = tsq * (1.0f/NV_CNT) - mean*mean;
    float rstd = rsqrtf(var + 1e-5f);
    float sc = gamma[cc]*rstd;
    scsh[cc]        = sc;
    scsh[1024 + cc] = beta[cc] - mean*sc;
  }
}

// K4: out = relu( x*(att_j*sc + 1) + sh ); nontemporal stores via ext_vector.
__global__ __launch_bounds__(256) void k4_out(const float* __restrict__ x,
    const float* __restrict__ att, const float* __restrict__ scsh,
    float* __restrict__ out){
  int f = blockIdx.x*256 + threadIdx.x;          // float4 index, < NC*17
  int n = blockIdx.x / 68;                       // uniform within block
  __shared__ float s_att[PP];
  if (threadIdx.x < PP) s_att[threadIdx.x] = att[n*PP + threadIdx.x];
  __syncthreads();
  int r = f/17;
  int q = f - r*17;
  int v0 = q*4;
  int c = r & (CC-1);
  float4 xv = ((const float4*)x)[f];
  float sc = scsh[c];
  float sh = scsh[1024 + c];
  float vals[4];
  #pragma unroll
  for (int j=0;j<4;j++){
    int p = part_of(v0 + j);
    float a = s_att[p];
    float e = (j==0)?xv.x:(j==1)?xv.y:(j==2)?xv.z:xv.w;
    vals[j] = fmaxf(fmaf(e, fmaf(a, sc, 1.0f), sh), 0.0f);
  }
  floatx4 ov; ov.x=vals[0]; ov.y=vals[1]; ov.z=vals[2]; ov.w=vals[3];
  __builtin_nontemporal_store(ov, ((floatx4*)out) + f);
}

extern "C" void kernel_launch(void* const* d_in, const int* in_sizes, int n_in,
                              void* d_out, int out_size, void* d_ws, size_t ws_size,
                              hipStream_t stream) {
  const float* x     = (const float*)d_in[0];
  const float* w1    = (const float*)d_in[1];
  const float* b1    = (const float*)d_in[2];
  const float* w2    = (const float*)d_in[3];
  const float* b2    = (const float*)d_in[4];
  const float* gamma = (const float*)d_in[5];
  const float* beta  = (const float*)d_in[6];
  float* out = (float*)d_out;

  float* w1p     = (float*)d_ws;                 // 256*1024 (1 MB)
  float* partial = w1p + OO*CC;                  // 512*2048 (4 MB)
  float* scsh    = partial + NN*2048;            // 2048
  float* att     = scsh + 2048;                  // 512*7
  // ~5 MB of ws; every buffer fully overwritten each call

  k0_prep     <<<256,         256, 0, stream>>>(w1, w1p);
  k12_att     <<<NN,          512, 0, stream>>>(x, w1p, b1, w2, b2, att, partial);
  k3b_finalize<<<32,          256, 0, stream>>>(partial, gamma, beta, scsh);
  k4_out      <<<(NC*17)/256, 256, 0, stream>>>(x, att, scsh, out);
}